// Round 3
// baseline (142.678 us; speedup 1.0000x reference)
//
#include <hip/hip_runtime.h>
#include <math.h>

// ---------------------------------------------------------------------------
// ConvLogicNetCIFAR forward. R3:
//  - fp16 activations (all gate outputs are in [0,1]; gates are 1-Lipschitz ->
//    storage rounding never amplifies; threshold 1.035 vs worst-case ~0.2)
//  - FC chain fc1->fc2->fc3->reduce backward-fused into ONE kernel via a
//    precomputed index/coef tree (7 gates, 8 conv reads per fc3 output);
//    removes ~60MB of intermediate traffic and 3 dispatches.
// Gate: c0 + c1*a + c2*b + c3*a*b, c = softmax(w_row)@COEF.
// Conv tree quirk: off=2^lvl-1 -> level0 rows0..3, level1 rows1..2, level2 row3.
// ---------------------------------------------------------------------------

#define B_SZ 128

__constant__ float c_coef_tbl[16][4] = {
    {0, 0, 0, 0}, {0, 0, 0, 1}, {0, 1, 0, -1}, {0, 1, 0, 0},
    {0, 0, 1, -1}, {0, 0, 1, 0}, {0, 1, 1, -2}, {0, 1, 1, -1},
    {1, -1, -1, 1}, {1, -1, -1, 2}, {1, 0, -1, 0}, {1, 0, -1, 1},
    {1, -1, 0, 0}, {1, -1, 0, 1}, {1, 0, 0, -1}, {1, 0, 0, 0}};

__device__ __forceinline__ float4 softmax_coef(const float* __restrict__ wr) {
  float m = -1e30f;
#pragma unroll
  for (int k = 0; k < 16; ++k) m = fmaxf(m, wr[k]);
  float e[16], s = 0.f;
#pragma unroll
  for (int k = 0; k < 16; ++k) { e[k] = __expf(wr[k] - m); s += e[k]; }
  float inv = 1.f / s;
  float c0 = 0.f, c1 = 0.f, c2 = 0.f, c3 = 0.f;
#pragma unroll
  for (int k = 0; k < 16; ++k) {
    c0 += e[k] * c_coef_tbl[k][0];
    c1 += e[k] * c_coef_tbl[k][1];
    c2 += e[k] * c_coef_tbl[k][2];
    c3 += e[k] * c_coef_tbl[k][3];
  }
  return make_float4(c0 * inv, c1 * inv, c2 * inv, c3 * inv);
}

__device__ __forceinline__ float gate_eval(float4 c, float a, float b) {
  return c.x + c.y * a + c.z * b + c.w * (a * b);
}

// Conv gate coefs (6784 float4): w1[0,128) w2[128,640) w3[640,2688) w4[2688,6784)
// gate g of oc: weight row oc*7 + (g&3).  Also zeroes d_out[0,1280).
__global__ void make_coef_conv(const float* __restrict__ w1, const float* __restrict__ w2,
                               const float* __restrict__ w3, const float* __restrict__ w4,
                               float4* __restrict__ coef, float* __restrict__ out_zero) {
  int g = blockIdx.x * blockDim.x + threadIdx.x;
  if (g < 1280) out_zero[g] = 0.f;
  if (g >= 6784) return;
  int gg; const float* w;
  if (g < 128)       { gg = g;        w = w1; }
  else if (g < 640)  { gg = g - 128;  w = w2; }
  else if (g < 2688) { gg = g - 640;  w = w3; }
  else               { gg = g - 2688; w = w4; }
  coef[g] = softmax_coef(w + ((gg >> 2) * 7 + (gg & 3)) * 16);
}

// Chase the FC index tree: per fc3 output o -> 8 conv-feature indices + 7 coefs.
// fc1: y1[j]=gate(cF1[j], x[ca1[j]], x[cb1[j]]); fc2: y2[k]=gate(cF2[k],y1[ca2[k]],y1[cb2[k]]);
// fc3: y3[o]=gate(cF3[o], y2[ca3[o]], y2[cb3[o]]).
__global__ void prep_fc(const float* __restrict__ fw1, const float* __restrict__ fw2,
                        const float* __restrict__ fw3,
                        const int* __restrict__ ca1, const int* __restrict__ cb1,
                        const int* __restrict__ ca2, const int* __restrict__ cb2,
                        const int* __restrict__ ca3, const int* __restrict__ cb3,
                        int* __restrict__ midx, float4* __restrict__ mcoef) {
  int o = blockIdx.x * blockDim.x + threadIdx.x;
  if (o >= 10240) return;
  int ka = ca3[o], kb = cb3[o];
  int j0 = ca2[ka], j1 = cb2[ka], j2 = ca2[kb], j3 = cb2[kb];
  int* mi = midx + o * 8;
  mi[0] = ca1[j0]; mi[1] = cb1[j0];
  mi[2] = ca1[j1]; mi[3] = cb1[j1];
  mi[4] = ca1[j2]; mi[5] = cb1[j2];
  mi[6] = ca1[j3]; mi[7] = cb1[j3];
  float4* mc = mcoef + o * 7;
  mc[0] = softmax_coef(fw1 + j0 * 16);
  mc[1] = softmax_coef(fw1 + j1 * 16);
  mc[2] = softmax_coef(fw1 + j2 * 16);
  mc[3] = softmax_coef(fw1 + j3 * 16);
  mc[4] = softmax_coef(fw2 + ka * 16);
  mc[5] = softmax_coef(fw2 + kb * 16);
  mc[6] = softmax_coef(fw3 + o * 16);
}

// x (128,3,32,32) fp32 -> xb [9][1024][128] fp16 binarized, via LDS transpose.
__global__ void binarize_transpose(const float* __restrict__ x, _Float16* __restrict__ out) {
  __shared__ float tile[64][65];
  int blk = blockIdx.x;
  int c = blk % 3; blk /= 3;
  int pt = blk % 16; blk /= 16;
  int b0 = blk * 64, p0 = pt * 64;
  int tp = threadIdx.x & 63;
  int tr = threadIdx.x >> 6;
#pragma unroll
  for (int r = 0; r < 16; ++r) {
    int bl = r * 4 + tr;
    tile[bl][tp] = x[((b0 + bl) * 3 + c) * 1024 + p0 + tp];
  }
  __syncthreads();
  int bl = threadIdx.x & 63;
  int pr = threadIdx.x >> 6;
#pragma unroll
  for (int r = 0; r < 16; ++r) {
    int pl = r * 4 + pr;
    float v = tile[bl][pl];
#pragma unroll
    for (int th = 0; th < 3; ++th) {
      float thr = (float)(th + 1) * 0.25f;
      out[((th * 3 + c) * 1024 + p0 + pl) * B_SZ + b0 + bl] =
          (_Float16)((v > thr) ? 1.f : 0.f);
    }
  }
}

// Feature-major conv tree + orpool, fp16 in/out. in [C][H][W][128], out [OC][PH][PW][128].
__global__ void conv_tree_pool_fm(const _Float16* __restrict__ in,
                                  const float4* __restrict__ coef,
                                  const int* __restrict__ leaf,
                                  _Float16* __restrict__ out,
                                  int C, int H, int W, int OC) {
  int tid = blockIdx.x * blockDim.x + threadIdx.x;
  int b = tid & 127;
  int t = tid >> 7;
  int PH = H >> 1, PW = W >> 1;
  int pw = t % PW; t /= PW;
  int ph = t % PH; t /= PH;
  int oc = t;
  if (oc >= OC) return;

  int lf[8];
#pragma unroll
  for (int l = 0; l < 8; ++l) lf[l] = leaf[oc * 8 + l];
  float4 c0 = coef[oc * 4 + 0];
  float4 c1 = coef[oc * 4 + 1];
  float4 c2 = coef[oc * 4 + 2];
  float4 c3 = coef[oc * 4 + 3];

  float best = -INFINITY;
#pragma unroll
  for (int py = 0; py < 2; ++py) {
#pragma unroll
    for (int px = 0; px < 2; ++px) {
      int i = 2 * ph + py, j = 2 * pw + px;
      float lv[8];
#pragma unroll
      for (int l = 0; l < 8; ++l) {
        int k = lf[l];
        int c = k / 9;
        int p = k - 9 * c;
        int di = p / 3;
        int dj = p - 3 * di;
        int ii = i + di - 1, jj = j + dj - 1;
        float v = 0.f;
        if ((unsigned)ii < (unsigned)H && (unsigned)jj < (unsigned)W)
          v = (float)in[((c * H + ii) * W + jj) * B_SZ + b];
        lv[l] = v;
      }
      float t0 = gate_eval(c0, lv[0], lv[1]);
      float t1 = gate_eval(c1, lv[2], lv[3]);
      float t2 = gate_eval(c2, lv[4], lv[5]);
      float t3 = gate_eval(c3, lv[6], lv[7]);
      float u0 = gate_eval(c1, t0, t1);
      float u1 = gate_eval(c2, t2, t3);
      best = fmaxf(best, gate_eval(c3, u0, u1));
    }
  }
  out[(oc * (PH * PW) + ph * PW + pw) * B_SZ + b] = best;
}

// Fused fc1+fc2+fc3+class-reduce.  x4 = conv4 output [4096][128] fp16.
// grid = 10 cls * 32 chunks; block = 128 (batch).  32 fc3 outputs per block,
// 7 gates + 8 gathered conv reads each; one atomicAdd per thread at the end.
__global__ void fused_fc(const _Float16* __restrict__ x4,
                         const int* __restrict__ midx,
                         const float4* __restrict__ mcoef,
                         float* __restrict__ out) {
  int b = threadIdx.x;
  int cls = blockIdx.x >> 5;
  int chunk = blockIdx.x & 31;
  int o0 = cls * 1024 + chunk * 32;
  float sum = 0.f;
  for (int t = 0; t < 32; ++t) {
    int o = o0 + t;
    const int* id = midx + o * 8;
    const float4* cf = mcoef + o * 7;
    float v[8];
#pragma unroll
    for (int l = 0; l < 8; ++l) v[l] = (float)x4[id[l] * B_SZ + b];
    float l0 = gate_eval(cf[0], v[0], v[1]);
    float l1 = gate_eval(cf[1], v[2], v[3]);
    float l2 = gate_eval(cf[2], v[4], v[5]);
    float l3 = gate_eval(cf[3], v[6], v[7]);
    float m0 = gate_eval(cf[4], l0, l1);
    float m1 = gate_eval(cf[5], l2, l3);
    sum += gate_eval(cf[6], m0, m1);
  }
  atomicAdd(&out[b * 10 + cls], sum * 0.1f);
}

extern "C" void kernel_launch(void* const* d_in, const int* in_sizes, int n_in,
                              void* d_out, int out_size, void* d_ws, size_t ws_size,
                              hipStream_t stream) {
  const float* x   = (const float*)d_in[0];
  const float* w1  = (const float*)d_in[1];
  const float* w2  = (const float*)d_in[2];
  const float* w3  = (const float*)d_in[3];
  const float* w4  = (const float*)d_in[4];
  const float* fw1 = (const float*)d_in[5];
  const float* fw2 = (const float*)d_in[6];
  const float* fw3 = (const float*)d_in[7];
  const int* l1  = (const int*)d_in[8];
  const int* l2  = (const int*)d_in[9];
  const int* l3  = (const int*)d_in[10];
  const int* l4  = (const int*)d_in[11];
  const int* ca1 = (const int*)d_in[12];
  const int* cb1 = (const int*)d_in[13];
  const int* ca2 = (const int*)d_in[14];
  const int* cb2 = (const int*)d_in[15];
  const int* ca3 = (const int*)d_in[16];
  const int* cb3 = (const int*)d_in[17];

  char* ws = (char*)d_ws;
  float4* coefC   = (float4*)ws;                 // 6784*16B = 108,544
  int*    midx    = (int*)(ws + 108544);         // 10240*8*4 = 327,680
  float4* mcoef   = (float4*)(ws + 108544 + 327680);          // 10240*7*16 = 1,146,880
  _Float16* xb    = (_Float16*)(ws + 108544 + 327680 + 1146880);   // 9216*128*2 = 2,359,296
  _Float16* bufA  = (_Float16*)(ws + 108544 + 327680 + 1146880 + 2359296);  // 2,097,152
  _Float16* bufB  = (_Float16*)(ws + 108544 + 327680 + 1146880 + 2359296 + 2097152);
  // total ~8.1 MB

  float4* cC1 = coefC;
  float4* cC2 = coefC + 128;
  float4* cC3 = coefC + 640;
  float4* cC4 = coefC + 2688;

  make_coef_conv<<<27, 256, 0, stream>>>(w1, w2, w3, w4, coefC, (float*)d_out);
  prep_fc<<<40, 256, 0, stream>>>(fw1, fw2, fw3, ca1, cb1, ca2, cb2, ca3, cb3,
                                  midx, mcoef);
  binarize_transpose<<<96, 256, 0, stream>>>(x, xb);

  conv_tree_pool_fm<<<4096, 256, 0, stream>>>(xb,   cC1, l1, bufA,   9, 32, 32,   32);
  conv_tree_pool_fm<<<4096, 256, 0, stream>>>(bufA, cC2, l2, bufB,  32, 16, 16,  128);
  conv_tree_pool_fm<<<4096, 256, 0, stream>>>(bufB, cC3, l3, bufA, 128,  8,  8,  512);
  conv_tree_pool_fm<<<2048, 256, 0, stream>>>(bufA, cC4, l4, bufB, 512,  4,  4, 1024);

  fused_fc<<<320, 128, 0, stream>>>(bufB, midx, mcoef, (float*)d_out);
}

// Round 4
// 126.105 us; speedup vs baseline: 1.1314x; 1.1314x over previous
//
#include <hip/hip_runtime.h>
#include <math.h>

// ---------------------------------------------------------------------------
// ConvLogicNetCIFAR forward. R4:
//  - fp16 activation storage, fp32 gate math (gates map [0,1]^2->[0,1];
//    storage rounding doesn't amplify; R3 measured absmax 0.0)
//  - conv kernels templated on (C,H,W,OC): address math strength-reduced
//  - FC chain fully fused (precomputed 8-index/7-coef tree per fc3 output),
//    now 640 blocks x 256 thr (~10 waves/CU) + unroll-2 MLP (R3 had 0.6
//    waves/SIMD -> latency-bound regression)
// Gate: c0 + c1*a + c2*b + c3*a*b, c = softmax(w_row)@COEF.
// Conv tree quirk: off=2^lvl-1 -> level0 rows0..3, level1 rows1..2, level2 row3.
// ---------------------------------------------------------------------------

#define B_SZ 128

__constant__ float c_coef_tbl[16][4] = {
    {0, 0, 0, 0}, {0, 0, 0, 1}, {0, 1, 0, -1}, {0, 1, 0, 0},
    {0, 0, 1, -1}, {0, 0, 1, 0}, {0, 1, 1, -2}, {0, 1, 1, -1},
    {1, -1, -1, 1}, {1, -1, -1, 2}, {1, 0, -1, 0}, {1, 0, -1, 1},
    {1, -1, 0, 0}, {1, -1, 0, 1}, {1, 0, 0, -1}, {1, 0, 0, 0}};

__device__ __forceinline__ float4 softmax_coef(const float* __restrict__ wr) {
  float m = -1e30f;
#pragma unroll
  for (int k = 0; k < 16; ++k) m = fmaxf(m, wr[k]);
  float e[16], s = 0.f;
#pragma unroll
  for (int k = 0; k < 16; ++k) { e[k] = __expf(wr[k] - m); s += e[k]; }
  float inv = 1.f / s;
  float c0 = 0.f, c1 = 0.f, c2 = 0.f, c3 = 0.f;
#pragma unroll
  for (int k = 0; k < 16; ++k) {
    c0 += e[k] * c_coef_tbl[k][0];
    c1 += e[k] * c_coef_tbl[k][1];
    c2 += e[k] * c_coef_tbl[k][2];
    c3 += e[k] * c_coef_tbl[k][3];
  }
  return make_float4(c0 * inv, c1 * inv, c2 * inv, c3 * inv);
}

__device__ __forceinline__ float gate_eval(float4 c, float a, float b) {
  return c.x + c.y * a + c.z * b + c.w * (a * b);
}

// Merged prep: conv gate coefs (g<6784), FC tree chase (6784<=g<17024),
// d_out zeroing (g<1280).
// conv coef layout: w1[0,128) w2[128,640) w3[640,2688) w4[2688,6784),
// gate g of oc -> weight row oc*7 + (g&3).
__global__ void prep_all(const float* __restrict__ w1, const float* __restrict__ w2,
                         const float* __restrict__ w3, const float* __restrict__ w4,
                         const float* __restrict__ fw1, const float* __restrict__ fw2,
                         const float* __restrict__ fw3,
                         const int* __restrict__ ca1, const int* __restrict__ cb1,
                         const int* __restrict__ ca2, const int* __restrict__ cb2,
                         const int* __restrict__ ca3, const int* __restrict__ cb3,
                         float4* __restrict__ coefC,
                         int* __restrict__ midx, float4* __restrict__ mcoef,
                         float* __restrict__ out_zero) {
  int g = blockIdx.x * blockDim.x + threadIdx.x;
  if (g < 1280) out_zero[g] = 0.f;
  if (g < 6784) {
    int gg; const float* w;
    if (g < 128)       { gg = g;        w = w1; }
    else if (g < 640)  { gg = g - 128;  w = w2; }
    else if (g < 2688) { gg = g - 640;  w = w3; }
    else               { gg = g - 2688; w = w4; }
    coefC[g] = softmax_coef(w + ((gg >> 2) * 7 + (gg & 3)) * 16);
  } else if (g < 17024) {
    int o = g - 6784;
    int ka = ca3[o], kb = cb3[o];
    int j0 = ca2[ka], j1 = cb2[ka], j2 = ca2[kb], j3 = cb2[kb];
    int* mi = midx + o * 8;
    mi[0] = ca1[j0]; mi[1] = cb1[j0];
    mi[2] = ca1[j1]; mi[3] = cb1[j1];
    mi[4] = ca1[j2]; mi[5] = cb1[j2];
    mi[6] = ca1[j3]; mi[7] = cb1[j3];
    float4* mc = mcoef + o * 7;
    mc[0] = softmax_coef(fw1 + j0 * 16);
    mc[1] = softmax_coef(fw1 + j1 * 16);
    mc[2] = softmax_coef(fw1 + j2 * 16);
    mc[3] = softmax_coef(fw1 + j3 * 16);
    mc[4] = softmax_coef(fw2 + ka * 16);
    mc[5] = softmax_coef(fw2 + kb * 16);
    mc[6] = softmax_coef(fw3 + o * 16);
  }
}

// x (128,3,32,32) fp32 -> xb [9][1024][128] fp16 binarized, via LDS transpose.
__global__ void binarize_transpose(const float* __restrict__ x, _Float16* __restrict__ out) {
  __shared__ float tile[64][65];
  int blk = blockIdx.x;
  int c = blk % 3; blk /= 3;
  int pt = blk % 16; blk /= 16;
  int b0 = blk * 64, p0 = pt * 64;
  int tp = threadIdx.x & 63;
  int tr = threadIdx.x >> 6;
#pragma unroll
  for (int r = 0; r < 16; ++r) {
    int bl = r * 4 + tr;
    tile[bl][tp] = x[((b0 + bl) * 3 + c) * 1024 + p0 + tp];
  }
  __syncthreads();
  int bl = threadIdx.x & 63;
  int pr = threadIdx.x >> 6;
#pragma unroll
  for (int r = 0; r < 16; ++r) {
    int pl = r * 4 + pr;
    float v = tile[bl][pl];
#pragma unroll
    for (int th = 0; th < 3; ++th) {
      float thr = (float)(th + 1) * 0.25f;
      out[((th * 3 + c) * 1024 + p0 + pl) * B_SZ + b0 + bl] =
          (_Float16)((v > thr) ? 1.f : 0.f);
    }
  }
}

// Feature-major conv tree + orpool, fp16 storage / fp32 math.
// in [C][H][W][128], out [OC][PH][PW][128].  Compile-time dims => shift addressing.
template <int C, int H, int W, int OC>
__global__ void conv_tree_pool_fm(const _Float16* __restrict__ in,
                                  const float4* __restrict__ coef,
                                  const int* __restrict__ leaf,
                                  _Float16* __restrict__ out) {
  constexpr int PH = H >> 1, PW = W >> 1;
  int tid = blockIdx.x * blockDim.x + threadIdx.x;
  int b = tid & 127;
  int t = tid >> 7;
  int pw = t % PW; t /= PW;
  int ph = t % PH; t /= PH;
  int oc = t;
  if (oc >= OC) return;

  // decode leaves once (px-invariant)
  int cc[8], di[8], dj[8];
#pragma unroll
  for (int l = 0; l < 8; ++l) {
    int k = leaf[oc * 8 + l];
    cc[l] = k / 9;
    int p = k - 9 * cc[l];
    di[l] = p / 3;
    dj[l] = p - 3 * di[l];
  }
  float4 c0 = coef[oc * 4 + 0];
  float4 c1 = coef[oc * 4 + 1];
  float4 c2 = coef[oc * 4 + 2];
  float4 c3 = coef[oc * 4 + 3];

  float best = -INFINITY;
#pragma unroll
  for (int py = 0; py < 2; ++py) {
#pragma unroll
    for (int px = 0; px < 2; ++px) {
      int i = 2 * ph + py, j = 2 * pw + px;
      float lv[8];
#pragma unroll
      for (int l = 0; l < 8; ++l) {
        int ii = i + di[l] - 1, jj = j + dj[l] - 1;
        float v = 0.f;
        if ((unsigned)ii < (unsigned)H && (unsigned)jj < (unsigned)W)
          v = (float)in[((cc[l] * H + ii) * W + jj) * B_SZ + b];
        lv[l] = v;
      }
      float t0 = gate_eval(c0, lv[0], lv[1]);
      float t1 = gate_eval(c1, lv[2], lv[3]);
      float t2 = gate_eval(c2, lv[4], lv[5]);
      float t3 = gate_eval(c3, lv[6], lv[7]);
      float u0 = gate_eval(c1, t0, t1);
      float u1 = gate_eval(c2, t2, t3);
      best = fmaxf(best, gate_eval(c3, u0, u1));
    }
  }
  out[(oc * (PH * PW) + ph * PW + pw) * B_SZ + b] = best;
}

// Fused fc1+fc2+fc3+class-reduce.  x4 [4096][128] fp16.
// grid = 10 cls * 64 chunks = 640 blocks, 256 threads:
// half h in {0,1} covers outputs o0+h*8 .. +8; each thread sums 8 fc3 outputs
// for its batch lane, halves combine via LDS, one atomic per (b,cls) per block.
__global__ void fused_fc(const _Float16* __restrict__ x4,
                         const int* __restrict__ midx,
                         const float4* __restrict__ mcoef,
                         float* __restrict__ out) {
  __shared__ float part[128];
  int b = threadIdx.x & 127;
  int h = threadIdx.x >> 7;
  int cls = blockIdx.x >> 6;
  int chunk = blockIdx.x & 63;
  int o0 = cls * 1024 + chunk * 16 + h * 8;
  float sum = 0.f;
#pragma unroll 2
  for (int t = 0; t < 8; ++t) {
    int o = o0 + t;
    const int* id = midx + o * 8;
    const float4* cf = mcoef + o * 7;
    float v[8];
#pragma unroll
    for (int l = 0; l < 8; ++l) v[l] = (float)x4[id[l] * B_SZ + b];
    float l0 = gate_eval(cf[0], v[0], v[1]);
    float l1 = gate_eval(cf[1], v[2], v[3]);
    float l2 = gate_eval(cf[2], v[4], v[5]);
    float l3 = gate_eval(cf[3], v[6], v[7]);
    float m0 = gate_eval(cf[4], l0, l1);
    float m1 = gate_eval(cf[5], l2, l3);
    sum += gate_eval(cf[6], m0, m1);
  }
  if (h == 1) part[b] = sum;
  __syncthreads();
  if (h == 0) atomicAdd(&out[b * 10 + cls], (sum + part[b]) * 0.1f);
}

extern "C" void kernel_launch(void* const* d_in, const int* in_sizes, int n_in,
                              void* d_out, int out_size, void* d_ws, size_t ws_size,
                              hipStream_t stream) {
  const float* x   = (const float*)d_in[0];
  const float* w1  = (const float*)d_in[1];
  const float* w2  = (const float*)d_in[2];
  const float* w3  = (const float*)d_in[3];
  const float* w4  = (const float*)d_in[4];
  const float* fw1 = (const float*)d_in[5];
  const float* fw2 = (const float*)d_in[6];
  const float* fw3 = (const float*)d_in[7];
  const int* l1  = (const int*)d_in[8];
  const int* l2  = (const int*)d_in[9];
  const int* l3  = (const int*)d_in[10];
  const int* l4  = (const int*)d_in[11];
  const int* ca1 = (const int*)d_in[12];
  const int* cb1 = (const int*)d_in[13];
  const int* ca2 = (const int*)d_in[14];
  const int* cb2 = (const int*)d_in[15];
  const int* ca3 = (const int*)d_in[16];
  const int* cb3 = (const int*)d_in[17];

  char* ws = (char*)d_ws;
  float4*  coefC = (float4*)ws;                              // 6784*16 = 108,544 B
  int*     midx  = (int*)(ws + 108544);                      // 327,680 B
  float4*  mcoef = (float4*)(ws + 108544 + 327680);          // 1,146,880 B
  _Float16* xb   = (_Float16*)(ws + 1583104);                // 2,359,296 B
  _Float16* bufA = (_Float16*)(ws + 1583104 + 2359296);      // 2,097,152 B
  _Float16* bufB = (_Float16*)(ws + 1583104 + 2359296 + 2097152);

  float4* cC1 = coefC;
  float4* cC2 = coefC + 128;
  float4* cC3 = coefC + 640;
  float4* cC4 = coefC + 2688;

  prep_all<<<67, 256, 0, stream>>>(w1, w2, w3, w4, fw1, fw2, fw3,
                                   ca1, cb1, ca2, cb2, ca3, cb3,
                                   coefC, midx, mcoef, (float*)d_out);
  binarize_transpose<<<96, 256, 0, stream>>>(x, xb);

  conv_tree_pool_fm<  9, 32, 32,   32><<<4096, 256, 0, stream>>>(xb,   cC1, l1, bufA);
  conv_tree_pool_fm< 32, 16, 16,  128><<<4096, 256, 0, stream>>>(bufA, cC2, l2, bufB);
  conv_tree_pool_fm<128,  8,  8,  512><<<4096, 256, 0, stream>>>(bufB, cC3, l3, bufA);
  conv_tree_pool_fm<512,  4,  4, 1024><<<2048, 256, 0, stream>>>(bufA, cC4, l4, bufB);

  fused_fc<<<640, 256, 0, stream>>>(bufB, midx, mcoef, (float*)d_out);
}

// Round 5
// 92.541 us; speedup vs baseline: 1.5418x; 1.3627x over previous
//
#include <hip/hip_runtime.h>
#include <math.h>

// ---------------------------------------------------------------------------
// ConvLogicNetCIFAR forward. R5:
//  - conv stages process 2 batch elems/thread (half2 loads: 256B/wave, half the
//    address VALU and load instructions)
//  - prep: one softmax per thread (7-way parallel over the FC tree; R4 did 7
//    serial dependent softmaxes per thread)
//  - fused FC: 4 outputs/thread unrolled, half2 gathers, LDS combine, partials
//    to ws + tiny reduce kernel (no atomics, deterministic)
// Gate: c0 + c1*a + c2*b + c3*a*b, c = softmax(w_row)@COEF.
// Conv tree quirk: off=2^lvl-1 -> level0 rows0..3, level1 rows1..2, level2 row3.
// ---------------------------------------------------------------------------

#define B_SZ 128

typedef _Float16 h2 __attribute__((ext_vector_type(2)));

__constant__ float c_coef_tbl[16][4] = {
    {0, 0, 0, 0}, {0, 0, 0, 1}, {0, 1, 0, -1}, {0, 1, 0, 0},
    {0, 0, 1, -1}, {0, 0, 1, 0}, {0, 1, 1, -2}, {0, 1, 1, -1},
    {1, -1, -1, 1}, {1, -1, -1, 2}, {1, 0, -1, 0}, {1, 0, -1, 1},
    {1, -1, 0, 0}, {1, -1, 0, 1}, {1, 0, 0, -1}, {1, 0, 0, 0}};

__device__ __forceinline__ float4 softmax_coef(const float* __restrict__ wr) {
  float m = -1e30f;
#pragma unroll
  for (int k = 0; k < 16; ++k) m = fmaxf(m, wr[k]);
  float e[16], s = 0.f;
#pragma unroll
  for (int k = 0; k < 16; ++k) { e[k] = __expf(wr[k] - m); s += e[k]; }
  float inv = 1.f / s;
  float c0 = 0.f, c1 = 0.f, c2 = 0.f, c3 = 0.f;
#pragma unroll
  for (int k = 0; k < 16; ++k) {
    c0 += e[k] * c_coef_tbl[k][0];
    c1 += e[k] * c_coef_tbl[k][1];
    c2 += e[k] * c_coef_tbl[k][2];
    c3 += e[k] * c_coef_tbl[k][3];
  }
  return make_float4(c0 * inv, c1 * inv, c2 * inv, c3 * inv);
}

__device__ __forceinline__ float gate_eval(float4 c, float a, float b) {
  return c.x + c.y * a + c.z * b + c.w * (a * b);
}
__device__ __forceinline__ float2 gate2(float4 c, float2 a, float2 b) {
  float2 r;
  r.x = c.x + c.y * a.x + c.z * b.x + c.w * (a.x * b.x);
  r.y = c.x + c.y * a.y + c.z * b.y + c.w * (a.y * b.y);
  return r;
}
__device__ __forceinline__ float2 h2f2(h2 v) {
  return make_float2((float)v[0], (float)v[1]);
}

// prep: g<71680 -> FC tree job (o=g/7, slot s=g%7: s<4 fc1-coef+midx pair,
// s<6 fc2-coef, s==6 fc3-coef); g in [71680,78464) -> conv gate coef
// (w1[0,128) w2[128,640) w3[640,2688) w4[2688,6784); gate g of oc -> row oc*7+(g&3)).
__global__ void prep_all(const float* __restrict__ w1, const float* __restrict__ w2,
                         const float* __restrict__ w3, const float* __restrict__ w4,
                         const float* __restrict__ fw1, const float* __restrict__ fw2,
                         const float* __restrict__ fw3,
                         const int* __restrict__ ca1, const int* __restrict__ cb1,
                         const int* __restrict__ ca2, const int* __restrict__ cb2,
                         const int* __restrict__ ca3, const int* __restrict__ cb3,
                         float4* __restrict__ coefC,
                         int* __restrict__ midx, float4* __restrict__ mcoef) {
  int g = blockIdx.x * blockDim.x + threadIdx.x;
  if (g < 71680) {
    int o = g / 7;
    int s = g - o * 7;
    if (s < 4) {
      int k = (s < 2) ? ca3[o] : cb3[o];
      int j = (s & 1) ? cb2[k] : ca2[k];
      midx[o * 8 + s * 2]     = ca1[j];
      midx[o * 8 + s * 2 + 1] = cb1[j];
      mcoef[o * 7 + s] = softmax_coef(fw1 + j * 16);
    } else if (s < 6) {
      int k = (s == 4) ? ca3[o] : cb3[o];
      mcoef[o * 7 + s] = softmax_coef(fw2 + k * 16);
    } else {
      mcoef[o * 7 + 6] = softmax_coef(fw3 + o * 16);
    }
  } else if (g < 78464) {
    int gg = g - 71680;
    const float* w;
    if (gg < 128)       {               w = w1; }
    else if (gg < 640)  { gg -= 128;    w = w2; }
    else if (gg < 2688) { gg -= 640;    w = w3; }
    else                { gg -= 2688;   w = w4; }
    coefC[g - 71680] = softmax_coef(w + ((gg >> 2) * 7 + (gg & 3)) * 16);
  }
}

// x (128,3,32,32) fp32 -> xb [9][1024][128] fp16 binarized, via LDS transpose.
__global__ void binarize_transpose(const float* __restrict__ x, _Float16* __restrict__ out) {
  __shared__ float tile[64][65];
  int blk = blockIdx.x;
  int c = blk % 3; blk /= 3;
  int pt = blk % 16; blk /= 16;
  int b0 = blk * 64, p0 = pt * 64;
  int tp = threadIdx.x & 63;
  int tr = threadIdx.x >> 6;
#pragma unroll
  for (int r = 0; r < 16; ++r) {
    int bl = r * 4 + tr;
    tile[bl][tp] = x[((b0 + bl) * 3 + c) * 1024 + p0 + tp];
  }
  __syncthreads();
  int bl = threadIdx.x & 63;
  int pr = threadIdx.x >> 6;
#pragma unroll
  for (int r = 0; r < 16; ++r) {
    int pl = r * 4 + pr;
    float v = tile[bl][pl];
#pragma unroll
    for (int th = 0; th < 3; ++th) {
      float thr = (float)(th + 1) * 0.25f;
      out[((th * 3 + c) * 1024 + p0 + pl) * B_SZ + b0 + bl] =
          (_Float16)((v > thr) ? 1.f : 0.f);
    }
  }
}

// Feature-major conv tree + orpool, 2 batch/thread.
// in [C][H][W][64] of h2, out [OC][PH][PW][64] of h2.
template <int C, int H, int W, int OC>
__global__ void conv_tree_pool_fm(const h2* __restrict__ in,
                                  const float4* __restrict__ coef,
                                  const int* __restrict__ leaf,
                                  h2* __restrict__ out) {
  constexpr int PH = H >> 1, PW = W >> 1;
  int tid = blockIdx.x * blockDim.x + threadIdx.x;
  int bp = tid & 63;
  int t = tid >> 6;
  int pw = t % PW; t /= PW;
  int ph = t % PH; t /= PH;
  int oc = t;
  if (oc >= OC) return;

  int cc[8], di[8], dj[8];
#pragma unroll
  for (int l = 0; l < 8; ++l) {
    int k = leaf[oc * 8 + l];
    cc[l] = k / 9;
    int p = k - 9 * cc[l];
    di[l] = p / 3;
    dj[l] = p - 3 * di[l];
  }
  float4 c0 = coef[oc * 4 + 0];
  float4 c1 = coef[oc * 4 + 1];
  float4 c2 = coef[oc * 4 + 2];
  float4 c3 = coef[oc * 4 + 3];

  float2 best = make_float2(-1e30f, -1e30f);
#pragma unroll
  for (int py = 0; py < 2; ++py) {
#pragma unroll
    for (int px = 0; px < 2; ++px) {
      int i = 2 * ph + py, j = 2 * pw + px;
      float2 lv[8];
#pragma unroll
      for (int l = 0; l < 8; ++l) {
        int ii = i + di[l] - 1, jj = j + dj[l] - 1;
        float2 v = make_float2(0.f, 0.f);
        if ((unsigned)ii < (unsigned)H && (unsigned)jj < (unsigned)W)
          v = h2f2(in[((cc[l] * H + ii) * W + jj) * 64 + bp]);
        lv[l] = v;
      }
      float2 t0 = gate2(c0, lv[0], lv[1]);
      float2 t1 = gate2(c1, lv[2], lv[3]);
      float2 t2 = gate2(c2, lv[4], lv[5]);
      float2 t3 = gate2(c3, lv[6], lv[7]);
      float2 u0 = gate2(c1, t0, t1);
      float2 u1 = gate2(c2, t2, t3);
      float2 o = gate2(c3, u0, u1);
      best.x = fmaxf(best.x, o.x);
      best.y = fmaxf(best.y, o.y);
    }
  }
  h2 r; r[0] = (_Float16)best.x; r[1] = (_Float16)best.y;
  out[(oc * (PH * PW) + ph * PW + pw) * 64 + bp] = r;
}

// Fused fc1+fc2+fc3, partial class sums. x4 [4096][64] h2.
// grid = 10 cls * 64 chunks; block 256 = 4 output-groups x 64 batch-pairs.
// Each thread: 4 fc3 outputs (fully unrolled) for its 2 batch lanes.
// Partials -> part[(cls*64+chunk)*64+bp] (float2).
__global__ void fused_fc(const h2* __restrict__ x4,
                         const int* __restrict__ midx,
                         const float4* __restrict__ mcoef,
                         float2* __restrict__ part) {
  __shared__ float2 red[4][64];
  int bp = threadIdx.x & 63;
  int g = threadIdx.x >> 6;
  int cls = blockIdx.x >> 6;
  int chunk = blockIdx.x & 63;
  int o0 = cls * 1024 + chunk * 16 + g * 4;
  float2 sum = make_float2(0.f, 0.f);
#pragma unroll
  for (int t = 0; t < 4; ++t) {
    int o = o0 + t;
    const int* id = midx + o * 8;
    const float4* cf = mcoef + o * 7;
    float2 v[8];
#pragma unroll
    for (int l = 0; l < 8; ++l) v[l] = h2f2(x4[id[l] * 64 + bp]);
    float2 l0 = gate2(cf[0], v[0], v[1]);
    float2 l1 = gate2(cf[1], v[2], v[3]);
    float2 l2 = gate2(cf[2], v[4], v[5]);
    float2 l3 = gate2(cf[3], v[6], v[7]);
    float2 m0 = gate2(cf[4], l0, l1);
    float2 m1 = gate2(cf[5], l2, l3);
    float2 y = gate2(cf[6], m0, m1);
    sum.x += y.x; sum.y += y.y;
  }
  red[g][bp] = sum;
  __syncthreads();
  if (g == 0) {
    float2 s = red[0][bp];
    s.x += red[1][bp].x + red[2][bp].x + red[3][bp].x;
    s.y += red[1][bp].y + red[2][bp].y + red[3][bp].y;
    part[(cls * 64 + chunk) * 64 + bp] = s;
  }
}

// out[b*10+cls] = 0.1 * sum_{chunk<64} part[(cls*64+chunk)][b]
__global__ void reduce_cls(const float* __restrict__ part, float* __restrict__ out) {
  int i = blockIdx.x * blockDim.x + threadIdx.x;
  if (i >= 1280) return;
  int cls = i >> 7;
  int b = i & 127;
  const float* base = part + (cls * 64) * 128 + b;
  float s = 0.f;
#pragma unroll
  for (int c = 0; c < 64; ++c) s += base[c * 128];
  out[b * 10 + cls] = s * 0.1f;
}

extern "C" void kernel_launch(void* const* d_in, const int* in_sizes, int n_in,
                              void* d_out, int out_size, void* d_ws, size_t ws_size,
                              hipStream_t stream) {
  const float* x   = (const float*)d_in[0];
  const float* w1  = (const float*)d_in[1];
  const float* w2  = (const float*)d_in[2];
  const float* w3  = (const float*)d_in[3];
  const float* w4  = (const float*)d_in[4];
  const float* fw1 = (const float*)d_in[5];
  const float* fw2 = (const float*)d_in[6];
  const float* fw3 = (const float*)d_in[7];
  const int* l1  = (const int*)d_in[8];
  const int* l2  = (const int*)d_in[9];
  const int* l3  = (const int*)d_in[10];
  const int* l4  = (const int*)d_in[11];
  const int* ca1 = (const int*)d_in[12];
  const int* cb1 = (const int*)d_in[13];
  const int* ca2 = (const int*)d_in[14];
  const int* cb2 = (const int*)d_in[15];
  const int* ca3 = (const int*)d_in[16];
  const int* cb3 = (const int*)d_in[17];

  char* ws = (char*)d_ws;
  float4*  coefC = (float4*)ws;                              // 108,544 B
  int*     midx  = (int*)(ws + 108544);                      // 327,680 B
  float4*  mcoef = (float4*)(ws + 108544 + 327680);          // 1,146,880 B
  _Float16* xb   = (_Float16*)(ws + 1583104);                // 2,359,296 B
  h2*      bufA  = (h2*)(ws + 1583104 + 2359296);            // 2,097,152 B
  h2*      bufB  = (h2*)(ws + 1583104 + 2359296 + 2097152);  // 2,097,152 B
  float2*  part  = (float2*)(ws + 1583104 + 2359296 + 2 * 2097152);  // 327,680 B

  float4* cC1 = coefC;
  float4* cC2 = coefC + 128;
  float4* cC3 = coefC + 640;
  float4* cC4 = coefC + 2688;

  prep_all<<<307, 256, 0, stream>>>(w1, w2, w3, w4, fw1, fw2, fw3,
                                    ca1, cb1, ca2, cb2, ca3, cb3,
                                    coefC, midx, mcoef);
  binarize_transpose<<<96, 256, 0, stream>>>(x, xb);

  conv_tree_pool_fm<  9, 32, 32,   32><<<2048, 256, 0, stream>>>((const h2*)xb, cC1, l1, bufA);
  conv_tree_pool_fm< 32, 16, 16,  128><<<2048, 256, 0, stream>>>(bufA, cC2, l2, bufB);
  conv_tree_pool_fm<128,  8,  8,  512><<<2048, 256, 0, stream>>>(bufB, cC3, l3, bufA);
  conv_tree_pool_fm<512,  4,  4, 1024><<<1024, 256, 0, stream>>>(bufA, cC4, l4, bufB);

  fused_fc<<<640, 256, 0, stream>>>(bufB, midx, mcoef, part);
  reduce_cls<<<5, 256, 0, stream>>>((const float*)part, (float*)d_out);
}

// Round 6
// 84.226 us; speedup vs baseline: 1.6940x; 1.0987x over previous
//
#include <hip/hip_runtime.h>
#include <math.h>

// ---------------------------------------------------------------------------
// ConvLogicNetCIFAR forward. R6: MEGAKERNEL.
// Evidence R1-R5: total ~= 10-12us * dispatch_count (per-dispatch floor
// dominates; all kernels are L2-resident and individually cheap). So: one
// block per batch element, entire conv tower + FC + class-sum in ONE kernel
// with LDS-resident activations. 2 dispatches total (prep + mega).
//  - LDS layout: zero-padded halos (no boundary checks) + PAIR-DUPLICATED
//    fp16 cells: cell (c,i,j) holds (v[i,j], v[i,j+1]) so one ds_read_b32
//    fetches both pooled-window columns -> half the LDS ops.
//  - packed v_pk_fma_f16 gate math (gates map [0,1]^2 -> [0,1]; error
//    ~2^-10/gate over ~12 levels -> ~0.02 total, threshold 1.035).
//  - per-thread output-channel ownership: leaf decode + coef splat hoisted.
// Gate: c0 + c1*a + c2*b + c3*(a*b), c = softmax(w_row)@COEF.
// Conv tree quirk: off=2^lvl-1 -> level0 rows0..3, level1 rows1..2, level2 row3.
// ---------------------------------------------------------------------------

typedef _Float16 h2 __attribute__((ext_vector_type(2)));

__constant__ float c_coef_tbl[16][4] = {
    {0, 0, 0, 0}, {0, 0, 0, 1}, {0, 1, 0, -1}, {0, 1, 0, 0},
    {0, 0, 1, -1}, {0, 0, 1, 0}, {0, 1, 1, -2}, {0, 1, 1, -1},
    {1, -1, -1, 1}, {1, -1, -1, 2}, {1, 0, -1, 0}, {1, 0, -1, 1},
    {1, -1, 0, 0}, {1, -1, 0, 1}, {1, 0, 0, -1}, {1, 0, 0, 0}};

__device__ __forceinline__ float4 softmax_coef(const float* __restrict__ wr) {
  float m = -1e30f;
#pragma unroll
  for (int k = 0; k < 16; ++k) m = fmaxf(m, wr[k]);
  float e[16], s = 0.f;
#pragma unroll
  for (int k = 0; k < 16; ++k) { e[k] = __expf(wr[k] - m); s += e[k]; }
  float inv = 1.f / s;
  float c0 = 0.f, c1 = 0.f, c2 = 0.f, c3 = 0.f;
#pragma unroll
  for (int k = 0; k < 16; ++k) {
    c0 += e[k] * c_coef_tbl[k][0];
    c1 += e[k] * c_coef_tbl[k][1];
    c2 += e[k] * c_coef_tbl[k][2];
    c3 += e[k] * c_coef_tbl[k][3];
  }
  return make_float4(c0 * inv, c1 * inv, c2 * inv, c3 * inv);
}

__device__ __forceinline__ float gate_eval(float4 c, float a, float b) {
  return c.x + c.y * a + c.z * b + c.w * (a * b);
}

// prep: g<71680 -> FC tree job (o=g/7, slot s=g%7): coefs compressed to fp16
// (mcoefh[o*28+s*4 ..]), indices to u16 (midx16[o*8 ..]).
// g in [71680,78464) -> conv gate coef float4 (w1[0,128) w2[128,640)
// w3[640,2688) w4[2688,6784); gate gg of oc -> weight row oc*7 + (gg&3)).
__global__ void prep_all(const float* __restrict__ w1, const float* __restrict__ w2,
                         const float* __restrict__ w3, const float* __restrict__ w4,
                         const float* __restrict__ fw1, const float* __restrict__ fw2,
                         const float* __restrict__ fw3,
                         const int* __restrict__ ca1, const int* __restrict__ cb1,
                         const int* __restrict__ ca2, const int* __restrict__ cb2,
                         const int* __restrict__ ca3, const int* __restrict__ cb3,
                         float4* __restrict__ coefC,
                         unsigned short* __restrict__ midx16,
                         _Float16* __restrict__ mcoefh) {
  int g = blockIdx.x * blockDim.x + threadIdx.x;
  if (g < 71680) {
    int o = g / 7;
    int s = g - o * 7;
    float4 c;
    if (s < 4) {
      int k = (s < 2) ? ca3[o] : cb3[o];
      int j = (s & 1) ? cb2[k] : ca2[k];
      midx16[o * 8 + s * 2]     = (unsigned short)ca1[j];
      midx16[o * 8 + s * 2 + 1] = (unsigned short)cb1[j];
      c = softmax_coef(fw1 + j * 16);
    } else if (s < 6) {
      int k = (s == 4) ? ca3[o] : cb3[o];
      c = softmax_coef(fw2 + k * 16);
    } else {
      c = softmax_coef(fw3 + o * 16);
    }
    _Float16* mc = mcoefh + o * 28 + s * 4;
    mc[0] = (_Float16)c.x; mc[1] = (_Float16)c.y;
    mc[2] = (_Float16)c.z; mc[3] = (_Float16)c.w;
  } else if (g < 78464) {
    int gg = g - 71680;
    int base = gg;
    const float* w;
    if (gg < 128)       {               w = w1; }
    else if (gg < 640)  { gg -= 128;    w = w2; }
    else if (gg < 2688) { gg -= 640;    w = w3; }
    else                { gg -= 2688;   w = w4; }
    coefC[base] = softmax_coef(w + ((gg >> 2) * 7 + (gg & 3)) * 16);
  }
}

// packed-fp16 gate on a px-pair
__device__ __forceinline__ h2 gateh(const h2* c, h2 a, h2 b) {
  return c[0] + c[1] * a + c[2] * b + c[3] * (a * b);
}

// One conv_tree+orpool stage, LDS->LDS, pair-duplicated padded layout.
// in: [C][H+2][W+2] h2 cells (cell(c,i,j) = (v[i][j], v[i][j+1]), halo 0).
// DUP out: [OC][PH+2][PW+2] h2 cells, same convention.  else plain fp16
// [OC][PH][PW] into outP.
template <int C, int H, int W, int OC, bool DUP>
__device__ void stage(const h2* __restrict__ in, h2* __restrict__ outD,
                      _Float16* __restrict__ outP,
                      const int* __restrict__ leaf,
                      const float4* __restrict__ coef, int tid) {
  constexpr int Hp = H + 2, Wp = W + 2;
  constexpr int PH = H / 2, PW = W / 2;
  constexpr int NPOS = PH * PW;
  constexpr int TPO = 1024 / OC;   // threads per output channel
  constexpr int ITER = NPOS / TPO; // outputs per thread
  constexpr int OWp = PW + 2;
  constexpr int OHWp = (PH + 2) * (PW + 2);

  int oc = tid / TPO;
  int lane = tid % TPO;

  // hoist: tap offsets + coef splats (oc-invariant per thread)
  int toff[8];
#pragma unroll
  for (int l = 0; l < 8; ++l) {
    int k = leaf[oc * 8 + l];
    int cc = k / 9;
    int p = k - 9 * cc;
    int di = p / 3;
    int dj = p - 3 * di;
    toff[l] = cc * (Hp * Wp) + di * Wp + dj;
  }
  h2 ch[4][4];
#pragma unroll
  for (int r = 0; r < 4; ++r) {
    float4 c = coef[oc * 4 + r];
    _Float16 x0 = (_Float16)c.x, x1 = (_Float16)c.y,
             x2 = (_Float16)c.z, x3 = (_Float16)c.w;
    ch[r][0][0] = x0; ch[r][0][1] = x0;
    ch[r][1][0] = x1; ch[r][1][1] = x1;
    ch[r][2][0] = x2; ch[r][2][1] = x2;
    ch[r][3][0] = x3; ch[r][3][1] = x3;
  }

#pragma unroll
  for (int it = 0; it < ITER; ++it) {
    int pos = lane + it * TPO;
    int pw = pos % PW, ph = pos / PW;
    h2 o01[2];
#pragma unroll
    for (int py = 0; py < 2; ++py) {
      int pbase = (2 * ph + py) * Wp + 2 * pw;
      h2 lv[8];
#pragma unroll
      for (int l = 0; l < 8; ++l) lv[l] = in[toff[l] + pbase];
      h2 t0 = gateh(ch[0], lv[0], lv[1]);
      h2 t1 = gateh(ch[1], lv[2], lv[3]);
      h2 t2 = gateh(ch[2], lv[4], lv[5]);
      h2 t3 = gateh(ch[3], lv[6], lv[7]);
      h2 u0 = gateh(ch[1], t0, t1);
      h2 u1 = gateh(ch[2], t2, t3);
      o01[py] = gateh(ch[3], u0, u1);
    }
    _Float16 m0 = o01[0][0] > o01[1][0] ? o01[0][0] : o01[1][0];
    _Float16 m1 = o01[0][1] > o01[1][1] ? o01[0][1] : o01[1][1];
    _Float16 v = m0 > m1 ? m0 : m1;
    if (DUP) {
      _Float16* oh = (_Float16*)outD;
      int cell = oc * OHWp + (ph + 1) * OWp + (pw + 1);
      oh[2 * cell] = v;      // lo of (ph+1, pw+1)
      oh[2 * cell - 1] = v;  // hi of left neighbor
    } else {
      outP[oc * NPOS + ph * PW + pw] = v;
    }
  }
}

__device__ __forceinline__ void zero_h2(h2* p, int n, int tid) {
  for (int i = tid; i < n; i += 1024) p[i] = h2{(_Float16)0, (_Float16)0};
}

// Megakernel: one block per batch element. 1024 threads.
__global__ __launch_bounds__(1024, 1) void mega(
    const float* __restrict__ x, const float4* __restrict__ coefC,
    const int* __restrict__ l1, const int* __restrict__ l2,
    const int* __restrict__ l3, const int* __restrict__ l4,
    const unsigned short* __restrict__ midx16,
    const _Float16* __restrict__ mcoefh, float* __restrict__ out) {
  __shared__ h2 A[12800];  // 51,200 B: xb(10404) / s2out(12800) / s4out(2048)
  __shared__ h2 B[18432];  // 73,728 B: s1out(10368) / s3out(18432)
  __shared__ float red[16][10];
  int tid = threadIdx.x;
  int b = blockIdx.x;

  // --- binarize x[b] -> A as dup-padded [9][34][34] ---
  zero_h2(A, 10404, tid);
  zero_h2(B, 10368, tid);
  __syncthreads();
  const float* xb_ = x + b * 3072;
  for (int cell = tid; cell < 9 * 34 * 34; cell += 1024) {
    int j = cell % 34;
    int t = cell / 34;
    int i = t % 34;
    int c9 = t / 34;
    int th = c9 / 3, c = c9 - 3 * th;
    float thr = (float)(th + 1) * 0.25f;
    _Float16 lo = (_Float16)0, hi = (_Float16)0;
    if (i >= 1 && i <= 32) {
      const float* row = xb_ + c * 1024 + (i - 1) * 32;
      if (j >= 1 && j <= 32) lo = (_Float16)((row[j - 1] > thr) ? 1.f : 0.f);
      if (j <= 31)           hi = (_Float16)((row[j] > thr) ? 1.f : 0.f);
    }
    A[cell] = h2{lo, hi};
  }
  __syncthreads();

  // --- conv tower ---
  stage<9, 32, 32, 32, true>(A, B, nullptr, l1, coefC, tid);
  __syncthreads();
  zero_h2(A, 12800, tid);
  __syncthreads();
  stage<32, 16, 16, 128, true>(B, A, nullptr, l2, coefC + 128, tid);
  __syncthreads();
  zero_h2(B, 18432, tid);
  __syncthreads();
  stage<128, 8, 8, 512, true>(A, B, nullptr, l3, coefC + 640, tid);
  __syncthreads();
  _Float16* Ah = (_Float16*)A;
  stage<512, 4, 4, 1024, false>(B, nullptr, Ah, l4, coefC + 2688, tid);
  __syncthreads();

  // --- fused FC: thread tid handles outputs o = k*1024 + tid, k = class ---
  float y[10];
  const uint4* mi = (const uint4*)midx16;      // 16B per output
  const uint2* mc = (const uint2*)mcoefh;      // 8B per gate (4 halfs)
#pragma unroll
  for (int k = 0; k < 10; ++k) {
    int o = k * 1024 + tid;
    uint4 I = mi[o];
    float v0 = (float)Ah[I.x & 0xffff], v1 = (float)Ah[I.x >> 16];
    float v2 = (float)Ah[I.y & 0xffff], v3 = (float)Ah[I.y >> 16];
    float v4 = (float)Ah[I.z & 0xffff], v5 = (float)Ah[I.z >> 16];
    float v6 = (float)Ah[I.w & 0xffff], v7 = (float)Ah[I.w >> 16];
    float4 cf[7];
#pragma unroll
    for (int gg = 0; gg < 7; ++gg) {
      uint2 u = mc[o * 7 + gg];
      h2 p0, p1;
      *(unsigned*)&p0 = u.x;
      *(unsigned*)&p1 = u.y;
      cf[gg] = make_float4((float)p0[0], (float)p0[1], (float)p1[0], (float)p1[1]);
    }
    float L0 = gate_eval(cf[0], v0, v1);
    float L1 = gate_eval(cf[1], v2, v3);
    float L2 = gate_eval(cf[2], v4, v5);
    float L3 = gate_eval(cf[3], v6, v7);
    float M0 = gate_eval(cf[4], L0, L1);
    float M1 = gate_eval(cf[5], L2, L3);
    y[k] = gate_eval(cf[6], M0, M1);
  }
#pragma unroll
  for (int k = 0; k < 10; ++k) {
    float v = y[k];
#pragma unroll
    for (int m = 32; m > 0; m >>= 1) v += __shfl_xor(v, m, 64);
    if ((tid & 63) == 0) red[tid >> 6][k] = v;
  }
  __syncthreads();
  if (tid < 10) {
    float s = 0.f;
#pragma unroll
    for (int w = 0; w < 16; ++w) s += red[w][tid];
    out[b * 10 + tid] = s * 0.1f;
  }
}

extern "C" void kernel_launch(void* const* d_in, const int* in_sizes, int n_in,
                              void* d_out, int out_size, void* d_ws, size_t ws_size,
                              hipStream_t stream) {
  const float* x   = (const float*)d_in[0];
  const float* w1  = (const float*)d_in[1];
  const float* w2  = (const float*)d_in[2];
  const float* w3  = (const float*)d_in[3];
  const float* w4  = (const float*)d_in[4];
  const float* fw1 = (const float*)d_in[5];
  const float* fw2 = (const float*)d_in[6];
  const float* fw3 = (const float*)d_in[7];
  const int* l1  = (const int*)d_in[8];
  const int* l2  = (const int*)d_in[9];
  const int* l3  = (const int*)d_in[10];
  const int* l4  = (const int*)d_in[11];
  const int* ca1 = (const int*)d_in[12];
  const int* cb1 = (const int*)d_in[13];
  const int* ca2 = (const int*)d_in[14];
  const int* cb2 = (const int*)d_in[15];
  const int* ca3 = (const int*)d_in[16];
  const int* cb3 = (const int*)d_in[17];

  char* ws = (char*)d_ws;
  float4*         coefC  = (float4*)ws;                      // 108,544 B
  unsigned short* midx16 = (unsigned short*)(ws + 108544);   // 163,840 B
  _Float16*       mcoefh = (_Float16*)(ws + 108544 + 163840);// 573,440 B

  prep_all<<<307, 256, 0, stream>>>(w1, w2, w3, w4, fw1, fw2, fw3,
                                    ca1, cb1, ca2, cb2, ca3, cb3,
                                    coefC, midx16, mcoefh);
  mega<<<128, 1024, 0, stream>>>(x, coefC, l1, l2, l3, l4, midx16, mcoefh,
                                 (float*)d_out);
}

// Round 7
// 62.845 us; speedup vs baseline: 2.2703x; 1.3402x over previous
//
#include <hip/hip_runtime.h>
#include <math.h>

// ---------------------------------------------------------------------------
// ConvLogicNetCIFAR forward. R7: megakernel (one block per batch element),
// spill fix.  R6 evidence: WRITE_SIZE=46.6MB on a 5KB-output kernel = scratch
// spills (~89 dwords/thread, matching the FC epilogue's live set), VGPR=64.
//  - __launch_bounds__(1024) only (16-wave block can afford up to 512 VGPR)
//  - FC epilogue STREAMED: one coef decoded at a time, per-class immediate
//    wave-reduce; no y[10]/cf[7] arrays.
// Conv tower unchanged from R6: LDS-resident, pair-duplicated padded fp16
// cells (one ds_read_b32 = both pooled-window columns), packed h2 gate math.
// Gate: c0 + c1*a + c2*b + c3*(a*b), c = softmax(w_row)@COEF.
// Conv tree quirk: off=2^lvl-1 -> level0 rows0..3, level1 rows1..2, level2 row3.
// ---------------------------------------------------------------------------

typedef _Float16 h2 __attribute__((ext_vector_type(2)));

__constant__ float c_coef_tbl[16][4] = {
    {0, 0, 0, 0}, {0, 0, 0, 1}, {0, 1, 0, -1}, {0, 1, 0, 0},
    {0, 0, 1, -1}, {0, 0, 1, 0}, {0, 1, 1, -2}, {0, 1, 1, -1},
    {1, -1, -1, 1}, {1, -1, -1, 2}, {1, 0, -1, 0}, {1, 0, -1, 1},
    {1, -1, 0, 0}, {1, -1, 0, 1}, {1, 0, 0, -1}, {1, 0, 0, 0}};

__device__ __forceinline__ float4 softmax_coef(const float* __restrict__ wr) {
  float m = -1e30f;
#pragma unroll
  for (int k = 0; k < 16; ++k) m = fmaxf(m, wr[k]);
  float e[16], s = 0.f;
#pragma unroll
  for (int k = 0; k < 16; ++k) { e[k] = __expf(wr[k] - m); s += e[k]; }
  float inv = 1.f / s;
  float c0 = 0.f, c1 = 0.f, c2 = 0.f, c3 = 0.f;
#pragma unroll
  for (int k = 0; k < 16; ++k) {
    c0 += e[k] * c_coef_tbl[k][0];
    c1 += e[k] * c_coef_tbl[k][1];
    c2 += e[k] * c_coef_tbl[k][2];
    c3 += e[k] * c_coef_tbl[k][3];
  }
  return make_float4(c0 * inv, c1 * inv, c2 * inv, c3 * inv);
}

__device__ __forceinline__ float gate_eval(float4 c, float a, float b) {
  return c.x + c.y * a + c.z * b + c.w * (a * b);
}

// prep: g<71680 -> FC tree job (o=g/7, slot s=g%7): coefs compressed to fp16
// (mcoefh[o*28+s*4 ..]), indices to u16 (midx16[o*8 ..]).
// g in [71680,78464) -> conv gate coef float4 (w1[0,128) w2[128,640)
// w3[640,2688) w4[2688,6784); gate gg of oc -> weight row oc*7 + (gg&3)).
__global__ void prep_all(const float* __restrict__ w1, const float* __restrict__ w2,
                         const float* __restrict__ w3, const float* __restrict__ w4,
                         const float* __restrict__ fw1, const float* __restrict__ fw2,
                         const float* __restrict__ fw3,
                         const int* __restrict__ ca1, const int* __restrict__ cb1,
                         const int* __restrict__ ca2, const int* __restrict__ cb2,
                         const int* __restrict__ ca3, const int* __restrict__ cb3,
                         float4* __restrict__ coefC,
                         unsigned short* __restrict__ midx16,
                         _Float16* __restrict__ mcoefh) {
  int g = blockIdx.x * blockDim.x + threadIdx.x;
  if (g < 71680) {
    int o = g / 7;
    int s = g - o * 7;
    float4 c;
    if (s < 4) {
      int k = (s < 2) ? ca3[o] : cb3[o];
      int j = (s & 1) ? cb2[k] : ca2[k];
      midx16[o * 8 + s * 2]     = (unsigned short)ca1[j];
      midx16[o * 8 + s * 2 + 1] = (unsigned short)cb1[j];
      c = softmax_coef(fw1 + j * 16);
    } else if (s < 6) {
      int k = (s == 4) ? ca3[o] : cb3[o];
      c = softmax_coef(fw2 + k * 16);
    } else {
      c = softmax_coef(fw3 + o * 16);
    }
    _Float16* mc = mcoefh + o * 28 + s * 4;
    mc[0] = (_Float16)c.x; mc[1] = (_Float16)c.y;
    mc[2] = (_Float16)c.z; mc[3] = (_Float16)c.w;
  } else if (g < 78464) {
    int gg = g - 71680;
    int base = gg;
    const float* w;
    if (gg < 128)       {               w = w1; }
    else if (gg < 640)  { gg -= 128;    w = w2; }
    else if (gg < 2688) { gg -= 640;    w = w3; }
    else                { gg -= 2688;   w = w4; }
    coefC[base] = softmax_coef(w + ((gg >> 2) * 7 + (gg & 3)) * 16);
  }
}

// packed-fp16 gate on a px-pair
__device__ __forceinline__ h2 gateh(const h2* c, h2 a, h2 b) {
  return c[0] + c[1] * a + c[2] * b + c[3] * (a * b);
}

// decode 4 packed fp16 coefs -> float4
__device__ __forceinline__ float4 dec_cf(uint2 u) {
  h2 p0, p1;
  *(unsigned*)&p0 = u.x;
  *(unsigned*)&p1 = u.y;
  return make_float4((float)p0[0], (float)p0[1], (float)p1[0], (float)p1[1]);
}

// One conv_tree+orpool stage, LDS->LDS, pair-duplicated padded layout.
// in: [C][H+2][W+2] h2 cells (cell(c,i,j) = (v[i][j], v[i][j+1]), halo 0).
// DUP out: [OC][PH+2][PW+2] h2 cells, same convention.  else plain fp16
// [OC][PH][PW] into outP.
template <int C, int H, int W, int OC, bool DUP>
__device__ void stage(const h2* __restrict__ in, h2* __restrict__ outD,
                      _Float16* __restrict__ outP,
                      const int* __restrict__ leaf,
                      const float4* __restrict__ coef, int tid) {
  constexpr int Hp = H + 2, Wp = W + 2;
  constexpr int PH = H / 2, PW = W / 2;
  constexpr int NPOS = PH * PW;
  constexpr int TPO = 1024 / OC;   // threads per output channel
  constexpr int ITER = NPOS / TPO; // outputs per thread
  constexpr int OWp = PW + 2;
  constexpr int OHWp = (PH + 2) * (PW + 2);

  int oc = tid / TPO;
  int lane = tid % TPO;

  // hoist: tap offsets + coef splats (oc-invariant per thread)
  int toff[8];
#pragma unroll
  for (int l = 0; l < 8; ++l) {
    int k = leaf[oc * 8 + l];
    int cc = k / 9;
    int p = k - 9 * cc;
    int di = p / 3;
    int dj = p - 3 * di;
    toff[l] = cc * (Hp * Wp) + di * Wp + dj;
  }
  h2 ch[4][4];
#pragma unroll
  for (int r = 0; r < 4; ++r) {
    float4 c = coef[oc * 4 + r];
    _Float16 x0 = (_Float16)c.x, x1 = (_Float16)c.y,
             x2 = (_Float16)c.z, x3 = (_Float16)c.w;
    ch[r][0][0] = x0; ch[r][0][1] = x0;
    ch[r][1][0] = x1; ch[r][1][1] = x1;
    ch[r][2][0] = x2; ch[r][2][1] = x2;
    ch[r][3][0] = x3; ch[r][3][1] = x3;
  }

#pragma unroll
  for (int it = 0; it < ITER; ++it) {
    int pos = lane + it * TPO;
    int pw = pos % PW, ph = pos / PW;
    h2 o01[2];
#pragma unroll
    for (int py = 0; py < 2; ++py) {
      int pbase = (2 * ph + py) * Wp + 2 * pw;
      h2 lv[8];
#pragma unroll
      for (int l = 0; l < 8; ++l) lv[l] = in[toff[l] + pbase];
      h2 t0 = gateh(ch[0], lv[0], lv[1]);
      h2 t1 = gateh(ch[1], lv[2], lv[3]);
      h2 t2 = gateh(ch[2], lv[4], lv[5]);
      h2 t3 = gateh(ch[3], lv[6], lv[7]);
      h2 u0 = gateh(ch[1], t0, t1);
      h2 u1 = gateh(ch[2], t2, t3);
      o01[py] = gateh(ch[3], u0, u1);
    }
    _Float16 m0 = o01[0][0] > o01[1][0] ? o01[0][0] : o01[1][0];
    _Float16 m1 = o01[0][1] > o01[1][1] ? o01[0][1] : o01[1][1];
    _Float16 v = m0 > m1 ? m0 : m1;
    if (DUP) {
      _Float16* oh = (_Float16*)outD;
      int cell = oc * OHWp + (ph + 1) * OWp + (pw + 1);
      oh[2 * cell] = v;      // lo of (ph+1, pw+1)
      oh[2 * cell - 1] = v;  // hi of left neighbor
    } else {
      outP[oc * NPOS + ph * PW + pw] = v;
    }
  }
}

__device__ __forceinline__ void zero_h2(h2* p, int n, int tid) {
  for (int i = tid; i < n; i += 1024) p[i] = h2{(_Float16)0, (_Float16)0};
}

// Megakernel: one block per batch element. 1024 threads.
// NOTE: __launch_bounds__(1024) ONLY -- a 16-wave block may hold up to 512
// VGPR/thread; R6's (1024,1) variant allocated 64 VGPR and spilled ~89
// dwords/thread to scratch (46.6MB global writes).
__global__ __launch_bounds__(1024) void mega(
    const float* __restrict__ x, const float4* __restrict__ coefC,
    const int* __restrict__ l1, const int* __restrict__ l2,
    const int* __restrict__ l3, const int* __restrict__ l4,
    const unsigned short* __restrict__ midx16,
    const _Float16* __restrict__ mcoefh, float* __restrict__ out) {
  __shared__ h2 A[12800];  // 51,200 B: xb(10404) / s2out(12800) / s4out(2048)
  __shared__ h2 B[18432];  // 73,728 B: s1out(10368) / s3out(18432)
  __shared__ float red[16][10];
  int tid = threadIdx.x;
  int b = blockIdx.x;

  // --- binarize x[b] -> A as dup-padded [9][34][34] ---
  zero_h2(A, 10404, tid);
  zero_h2(B, 10368, tid);
  __syncthreads();
  const float* xb_ = x + b * 3072;
  for (int cell = tid; cell < 9 * 34 * 34; cell += 1024) {
    int j = cell % 34;
    int t = cell / 34;
    int i = t % 34;
    int c9 = t / 34;
    int th = c9 / 3, c = c9 - 3 * th;
    float thr = (float)(th + 1) * 0.25f;
    _Float16 lo = (_Float16)0, hi = (_Float16)0;
    if (i >= 1 && i <= 32) {
      const float* row = xb_ + c * 1024 + (i - 1) * 32;
      if (j >= 1 && j <= 32) lo = (_Float16)((row[j - 1] > thr) ? 1.f : 0.f);
      if (j <= 31)           hi = (_Float16)((row[j] > thr) ? 1.f : 0.f);
    }
    A[cell] = h2{lo, hi};
  }
  __syncthreads();

  // --- conv tower ---
  stage<9, 32, 32, 32, true>(A, B, nullptr, l1, coefC, tid);
  __syncthreads();
  zero_h2(A, 12800, tid);
  __syncthreads();
  stage<32, 16, 16, 128, true>(B, A, nullptr, l2, coefC + 128, tid);
  __syncthreads();
  zero_h2(B, 18432, tid);
  __syncthreads();
  stage<128, 8, 8, 512, true>(A, B, nullptr, l3, coefC + 640, tid);
  __syncthreads();
  _Float16* Ah = (_Float16*)A;
  stage<512, 4, 4, 1024, false>(B, nullptr, Ah, l4, coefC + 2688, tid);
  __syncthreads();

  // --- fused FC, STREAMED: thread tid handles outputs o = k*1024 + tid ---
  // per-class: decode coefs one at a time, compute y, immediately wave-reduce.
  const uint4* mi = (const uint4*)midx16;  // 16B per output (8 u16 indices)
  const uint2* mc = (const uint2*)mcoefh;  // 8B per gate (4 halfs)
  int wid = tid >> 6;
#pragma unroll
  for (int k = 0; k < 10; ++k) {
    int o = k * 1024 + tid;
    uint4 I = mi[o];
    const uint2* cfp = mc + o * 7;
    float L0 = gate_eval(dec_cf(cfp[0]), (float)Ah[I.x & 0xffff], (float)Ah[I.x >> 16]);
    float L1 = gate_eval(dec_cf(cfp[1]), (float)Ah[I.y & 0xffff], (float)Ah[I.y >> 16]);
    float L2 = gate_eval(dec_cf(cfp[2]), (float)Ah[I.z & 0xffff], (float)Ah[I.z >> 16]);
    float L3 = gate_eval(dec_cf(cfp[3]), (float)Ah[I.w & 0xffff], (float)Ah[I.w >> 16]);
    float M0 = gate_eval(dec_cf(cfp[4]), L0, L1);
    float M1 = gate_eval(dec_cf(cfp[5]), L2, L3);
    float y = gate_eval(dec_cf(cfp[6]), M0, M1);
#pragma unroll
    for (int m = 32; m > 0; m >>= 1) y += __shfl_xor(y, m, 64);
    if ((tid & 63) == 0) red[wid][k] = y;
  }
  __syncthreads();
  if (tid < 10) {
    float s = 0.f;
#pragma unroll
    for (int w = 0; w < 16; ++w) s += red[w][tid];
    out[b * 10 + tid] = s * 0.1f;
  }
}

extern "C" void kernel_launch(void* const* d_in, const int* in_sizes, int n_in,
                              void* d_out, int out_size, void* d_ws, size_t ws_size,
                              hipStream_t stream) {
  const float* x   = (const float*)d_in[0];
  const float* w1  = (const float*)d_in[1];
  const float* w2  = (const float*)d_in[2];
  const float* w3  = (const float*)d_in[3];
  const float* w4  = (const float*)d_in[4];
  const float* fw1 = (const float*)d_in[5];
  const float* fw2 = (const float*)d_in[6];
  const float* fw3 = (const float*)d_in[7];
  const int* l1  = (const int*)d_in[8];
  const int* l2  = (const int*)d_in[9];
  const int* l3  = (const int*)d_in[10];
  const int* l4  = (const int*)d_in[11];
  const int* ca1 = (const int*)d_in[12];
  const int* cb1 = (const int*)d_in[13];
  const int* ca2 = (const int*)d_in[14];
  const int* cb2 = (const int*)d_in[15];
  const int* ca3 = (const int*)d_in[16];
  const int* cb3 = (const int*)d_in[17];

  char* ws = (char*)d_ws;
  float4*         coefC  = (float4*)ws;                      // 108,544 B
  unsigned short* midx16 = (unsigned short*)(ws + 108544);   // 163,840 B
  _Float16*       mcoefh = (_Float16*)(ws + 108544 + 163840);// 573,440 B

  prep_all<<<307, 256, 0, stream>>>(w1, w2, w3, w4, fw1, fw2, fw3,
                                    ca1, cb1, ca2, cb2, ca3, cb3,
                                    coefC, midx16, mcoefh);
  mega<<<128, 1024, 0, stream>>>(x, coefC, l1, l2, l3, l4, midx16, mcoefh,
                                 (float*)d_out);
}